// Round 2
// baseline (372.167 us; speedup 1.0000x reference)
//
#include <hip/hip_runtime.h>
#include <hip/hip_bf16.h>

// Problem constants (reference: Edges GNN message MLP)
#define FEAT     64
#define NMU      100
#define K1_REAL  228      // 2*FEAT + NMU
#define K1_PAD   256      // padded K for layer 1 (8 steps of 32)
#define HID      128
#define ODIM     64
#define K2       128
#define MTILE    64       // edges per block
#define LDA1     264      // A-tile leading dim (bf16 elems): 256 + 8 pad
#define LDH      132      // H-tile leading dim: 128 + 4 pad (4-row stride = 8 mod 32 dwords -> conflict-free epilogue stores)

typedef __bf16 bf16x8 __attribute__((ext_vector_type(8)));
typedef __bf16 bf16x4 __attribute__((ext_vector_type(4)));
typedef float  fx4    __attribute__((ext_vector_type(4)));

// Pack W1 [HID=128, K1_REAL=228] and W2 [ODIM=64, K2=128] fp32 -> bf16
// MFMA B-fragment order in one kernel.
// B1[((kk*4+q)*128 + n)*8 + j] = W1[n][kk*32 + q*8 + j]  (0 if k >= 228), 32768 elems
// B2[((kk*4+q)*64  + n)*8 + j] = W2[n][kk*32 + q*8 + j],                   8192 elems
__global__ void pack_w(const float* __restrict__ W1, const float* __restrict__ W2,
                       __bf16* __restrict__ B1, __bf16* __restrict__ B2) {
    int i = blockIdx.x * 256 + threadIdx.x;     // 0..40959
    if (i < 32768) {
        int j  = i & 7;
        int n  = (i >> 3) & 127;
        int qk = i >> 10;                       // kk*4 + q, 0..31
        int k  = (qk >> 2) * 32 + (qk & 3) * 8 + j;
        float v = (k < K1_REAL) ? W1[n * K1_REAL + k] : 0.0f;
        B1[i] = (__bf16)v;
    } else {
        int t = i - 32768;                      // 0..8191
        int j  = t & 7;
        int n  = (t >> 3) & 63;
        int qk = t >> 9;                        // 0..15
        int k  = (qk >> 2) * 32 + (qk & 3) * 8 + j;
        B2[t] = (__bf16)W2[n * K2 + k];
    }
}

__global__ __launch_bounds__(256)
void edges_fused(const float* __restrict__ h,
                 const int*   __restrict__ src,
                 const int*   __restrict__ dst,
                 const float* __restrict__ enorm,
                 const float* __restrict__ mu,
                 const __bf16* __restrict__ B1,
                 const __bf16* __restrict__ B2,
                 float* __restrict__ out) {
    // Atile (64 x 264 bf16 = 33792 B) and Htile (64 x 132 = 16896 B) are
    // time-disjoint: Htile aliases the same buffer. LDS/block = 33792 B
    // -> 4 blocks/CU (was 51200 B -> 3 blocks/CU).
    __shared__ __bf16 S[MTILE * LDA1];
    __bf16* Atile = S;
    __bf16* Htile = S;

    const int tid = threadIdx.x;
    const int e0  = blockIdx.x * MTILE;

    // ---- Stage 1: build A-tile (64 rows x [h_src(64) | h_dst(64) | rbf(100) | 0-pad(28)]) ----
    {
        // Gather: 4 threads per row; p=0,1 -> src halves, p=2,3 -> dst halves
        int r = tid >> 2, p = tid & 3;
        int e = e0 + r;
        int node = (p < 2) ? src[e] : dst[e];
        int half = p & 1;
        const float4* hp = (const float4*)(h + (size_t)node * FEAT + half * 32);
        __bf16* ap = &Atile[r * LDA1 + (p >> 1) * FEAT + half * 32];
#pragma unroll
        for (int i = 0; i < 8; ++i) {
            float4 v = hp[i];
            bf16x4 o = { (__bf16)v.x, (__bf16)v.y, (__bf16)v.z, (__bf16)v.w };
            *(bf16x4*)(ap + i * 4) = o;
        }
    }
    {
        // RBF: 4 threads per row, 25 mus each; then zero-pad cols 228..255
        int r = tid >> 2, g = tid & 3;
        float d = enorm[e0 + r];
        __bf16* ap = &Atile[r * LDA1 + 2 * FEAT];
        int j0 = g * 25;
#pragma unroll
        for (int jj = 0; jj < 25; ++jj) {
            int j = j0 + jj;
            float t = mu[j] - d;
            ap[j] = (__bf16)__expf(-10.0f * t * t);
        }
        __bf16* zp = &Atile[r * LDA1 + K1_REAL + g * 7];
#pragma unroll
        for (int c = 0; c < 7; ++c) zp[c] = (__bf16)0.0f;
    }
    __syncthreads();

    const int lane = tid & 63;
    const int w    = tid >> 6;    // wave 0..3: owns N-tiles {2w, 2w+1} of layer 1
    const int ln   = lane & 15;
    const int q    = lane >> 4;

    // ---- Layer 1: [64 x 256] @ [256 x 128] -> silu -> Htile ----
    fx4 acc[4][2];
#pragma unroll
    for (int mt = 0; mt < 4; ++mt)
#pragma unroll
        for (int ntl = 0; ntl < 2; ++ntl)
            acc[mt][ntl] = (fx4){0.f, 0.f, 0.f, 0.f};

    const bf16x8* pB1 = (const bf16x8*)B1;
#pragma unroll
    for (int kk = 0; kk < 8; ++kk) {
        const int kof = kk * 32 + q * 8;
        bf16x8 a[4];
#pragma unroll
        for (int mt = 0; mt < 4; ++mt)
            a[mt] = *(const bf16x8*)&Atile[(mt * 16 + ln) * LDA1 + kof];
        bf16x8 b[2];
#pragma unroll
        for (int ntl = 0; ntl < 2; ++ntl)
            b[ntl] = pB1[(kk * 4 + q) * 128 + (w * 2 + ntl) * 16 + ln];
#pragma unroll
        for (int mt = 0; mt < 4; ++mt)
#pragma unroll
            for (int ntl = 0; ntl < 2; ++ntl)
                acc[mt][ntl] = __builtin_amdgcn_mfma_f32_16x16x32_bf16(
                    a[mt], b[ntl], acc[mt][ntl], 0, 0, 0);
    }

    // All reads of Atile must complete chip-wide before Htile overwrites it.
    __syncthreads();

    // SiLU, convert to bf16, write H-tile.
    // C/D layout: col = lane&15, row = q*4 + reg  (within each 16x16 tile)
#pragma unroll
    for (int mt = 0; mt < 4; ++mt) {
#pragma unroll
        for (int ntl = 0; ntl < 2; ++ntl) {
#pragma unroll
            for (int r = 0; r < 4; ++r) {
                float z = acc[mt][ntl][r];
                float s = z / (1.0f + __expf(-z));
                int row = mt * 16 + q * 4 + r;
                int col = (w * 2 + ntl) * 16 + ln;
                Htile[row * LDH + col] = (__bf16)s;
            }
        }
    }
    __syncthreads();

    // ---- Layer 2: [64 x 128] @ [128 x 64] -> out ----
    fx4 acc2[4];
#pragma unroll
    for (int mt = 0; mt < 4; ++mt) acc2[mt] = (fx4){0.f, 0.f, 0.f, 0.f};

    const bf16x8* pB2 = (const bf16x8*)B2;
#pragma unroll
    for (int kk = 0; kk < 4; ++kk) {
        const int kof = kk * 32 + q * 8;
        bf16x8 b2 = pB2[(kk * 4 + q) * 64 + w * 16 + ln];
#pragma unroll
        for (int mt = 0; mt < 4; ++mt) {
            bf16x8 a2 = *(const bf16x8*)&Htile[(mt * 16 + ln) * LDH + kof];
            acc2[mt] = __builtin_amdgcn_mfma_f32_16x16x32_bf16(a2, b2, acc2[mt], 0, 0, 0);
        }
    }

    // Store: wave w owns output cols [16w, 16w+16)
#pragma unroll
    for (int mt = 0; mt < 4; ++mt) {
#pragma unroll
        for (int r = 0; r < 4; ++r) {
            int row = mt * 16 + q * 4 + r;
            int col = w * 16 + ln;
            out[(size_t)(e0 + row) * ODIM + col] = acc2[mt][r];
        }
    }
}

extern "C" void kernel_launch(void* const* d_in, const int* in_sizes, int n_in,
                              void* d_out, int out_size, void* d_ws, size_t ws_size,
                              hipStream_t stream) {
    const float* h   = (const float*)d_in[0];
    const int*   src = (const int*)d_in[1];
    const int*   dst = (const int*)d_in[2];
    const float* en  = (const float*)d_in[3];
    const float* mu  = (const float*)d_in[4];
    const float* W1  = (const float*)d_in[5];
    const float* W2  = (const float*)d_in[6];

    __bf16* B1 = (__bf16*)d_ws;                          // 32768 bf16 = 64 KB
    __bf16* B2 = (__bf16*)((char*)d_ws + 65536);         // 8192 bf16  = 16 KB

    pack_w<<<160, 256, 0, stream>>>(W1, W2, B1, B2);

    const int E = in_sizes[1];                 // 800000, divisible by MTILE
    const int nblocks = E / MTILE;             // 12500
    edges_fused<<<nblocks, 256, 0, stream>>>(h, src, dst, en, mu, B1, B2, (float*)d_out);
}

// Round 3
// 338.191 us; speedup vs baseline: 1.1005x; 1.1005x over previous
//
#include <hip/hip_runtime.h>
#include <hip/hip_bf16.h>

// Edges GNN message MLP: per-edge RBF(100) + gather h[src],h[dst] (64+64)
// -> Linear(228->128) -> SiLU -> Linear(128->64).
// R3 design: barrier-free. Each wave owns WEDGES=32 edges end-to-end.
// A-fragments come straight from global (gather) / registers (RBF); the only
// LDS use is a wave-private tile for the layer1->layer2 fragment transpose.

#define FEAT     64
#define NMU      100
#define K1_REAL  228
#define HID      128
#define ODIM     64
#define K2       128
#define WEDGES   32        // edges per wave
#define BEDGES   128       // 4 waves/block
#define LDH2     136       // bf16 leading dim of per-wave H tile (16B-aligned rows)

typedef __bf16 bf16x8 __attribute__((ext_vector_type(8)));
typedef float  fx4    __attribute__((ext_vector_type(4)));

// Pack W1 [128 x 228] and W2 [64 x 128] fp32 -> bf16 MFMA B-fragment order.
// B1[((kk*4+q)*128 + n)*8 + j] = W1[n][kk*32 + q*8 + j]  (0 if k >= 228)
// B2[((kk*4+q)*64  + n)*8 + j] = W2[n][kk*32 + q*8 + j]
__global__ void pack_w(const float* __restrict__ W1, const float* __restrict__ W2,
                       __bf16* __restrict__ B1, __bf16* __restrict__ B2) {
    int i = blockIdx.x * 256 + threadIdx.x;     // 0..40959
    if (i < 32768) {
        int j  = i & 7;
        int n  = (i >> 3) & 127;
        int qk = i >> 10;
        int k  = (qk >> 2) * 32 + (qk & 3) * 8 + j;
        float v = (k < K1_REAL) ? W1[n * K1_REAL + k] : 0.0f;
        B1[i] = (__bf16)v;
    } else {
        int t = i - 32768;
        int j  = t & 7;
        int n  = (t >> 3) & 63;
        int qk = t >> 9;
        int k  = (qk >> 2) * 32 + (qk & 3) * 8 + j;
        B2[t] = (__bf16)W2[n * K2 + k];
    }
}

__device__ __forceinline__ bf16x8 hfrag(const float* __restrict__ h, int node, int cb) {
    const float4* p = (const float4*)(h + (size_t)node * FEAT + cb);
    float4 v0 = p[0];
    float4 v1 = p[1];
    bf16x8 a = { (__bf16)v0.x, (__bf16)v0.y, (__bf16)v0.z, (__bf16)v0.w,
                 (__bf16)v1.x, (__bf16)v1.y, (__bf16)v1.z, (__bf16)v1.w };
    return a;
}

__global__ __launch_bounds__(256, 4)
void edges_fused(const float* __restrict__ h,
                 const int*   __restrict__ src,
                 const int*   __restrict__ dst,
                 const float* __restrict__ enorm,
                 const float* __restrict__ mu,
                 const __bf16* __restrict__ B1,
                 const __bf16* __restrict__ B2,
                 float* __restrict__ out) {
    // Wave-private H tiles: 4 waves x 32 rows x 136 bf16 = 34816 B -> 4 blocks/CU.
    __shared__ __bf16 Hs[4 * WEDGES * LDH2];

    const int tid  = threadIdx.x;
    const int w    = tid >> 6;
    const int lane = tid & 63;
    const int ln   = lane & 15;
    const int q    = lane >> 4;
    const int g0   = blockIdx.x * BEDGES + w * WEDGES;

    // Per-m-tile edge data (rows ln of each 16-row slab; uniform across q).
    int nsrc[2], ndst[2];
    float dval[2];
#pragma unroll
    for (int mt = 0; mt < 2; ++mt) {
        int e = g0 + mt * 16 + ln;
        nsrc[mt] = src[e];
        ndst[mt] = dst[e];
        dval[mt] = enorm[e];
    }

    // ---- Layer 1: [32 x 256pad] @ [256 x 128] ----
    fx4 acc1[2][8];
#pragma unroll
    for (int mt = 0; mt < 2; ++mt)
#pragma unroll
        for (int nt = 0; nt < 8; ++nt)
            acc1[mt][nt] = (fx4){0.f, 0.f, 0.f, 0.f};

    const bf16x8* pB1 = (const bf16x8*)B1;

    // kk = 0..3: gathered node features (src halves then dst halves)
#pragma unroll
    for (int kk = 0; kk < 4; ++kk) {
        const int cb = (kk & 1) * 32 + q * 8;
        bf16x8 a[2];
#pragma unroll
        for (int mt = 0; mt < 2; ++mt) {
            int node = (kk < 2) ? nsrc[mt] : ndst[mt];
            a[mt] = hfrag(h, node, cb);
        }
#pragma unroll
        for (int nt = 0; nt < 8; ++nt) {
            bf16x8 b = pB1[(kk * 4 + q) * 128 + nt * 16 + ln];
            acc1[0][nt] = __builtin_amdgcn_mfma_f32_16x16x32_bf16(a[0], b, acc1[0][nt], 0, 0, 0);
            acc1[1][nt] = __builtin_amdgcn_mfma_f32_16x16x32_bf16(a[1], b, acc1[1][nt], 0, 0, 0);
        }
    }

    // kk = 4..6: RBF columns c0 = (kk-4)*32 + q*8 .. +7, all < 100
#pragma unroll
    for (int kk = 4; kk < 7; ++kk) {
        const int c0 = (kk - 4) * 32 + q * 8;
        float4 m0 = *(const float4*)(mu + c0);
        float4 m1 = *(const float4*)(mu + c0 + 4);
        bf16x8 a[2];
#pragma unroll
        for (int mt = 0; mt < 2; ++mt) {
            float d = dval[mt];
            float t0 = m0.x - d, t1 = m0.y - d, t2 = m0.z - d, t3 = m0.w - d;
            float t4 = m1.x - d, t5 = m1.y - d, t6 = m1.z - d, t7 = m1.w - d;
            a[mt] = (bf16x8){ (__bf16)__expf(-10.f * t0 * t0), (__bf16)__expf(-10.f * t1 * t1),
                              (__bf16)__expf(-10.f * t2 * t2), (__bf16)__expf(-10.f * t3 * t3),
                              (__bf16)__expf(-10.f * t4 * t4), (__bf16)__expf(-10.f * t5 * t5),
                              (__bf16)__expf(-10.f * t6 * t6), (__bf16)__expf(-10.f * t7 * t7) };
        }
#pragma unroll
        for (int nt = 0; nt < 8; ++nt) {
            bf16x8 b = pB1[(kk * 4 + q) * 128 + nt * 16 + ln];
            acc1[0][nt] = __builtin_amdgcn_mfma_f32_16x16x32_bf16(a[0], b, acc1[0][nt], 0, 0, 0);
            acc1[1][nt] = __builtin_amdgcn_mfma_f32_16x16x32_bf16(a[1], b, acc1[1][nt], 0, 0, 0);
        }
    }

    // kk = 7: only q==0 lanes carry real values (RBF cols 96..99), rest zero.
    {
        float4 m7 = *(const float4*)(mu + 96);
        const __bf16 zz = (__bf16)0.0f;
        const bool qz = (q == 0);
        bf16x8 a[2];
#pragma unroll
        for (int mt = 0; mt < 2; ++mt) {
            float d = dval[mt];
            float t0 = m7.x - d, t1 = m7.y - d, t2 = m7.z - d, t3 = m7.w - d;
            a[mt] = (bf16x8){ qz ? (__bf16)__expf(-10.f * t0 * t0) : zz,
                              qz ? (__bf16)__expf(-10.f * t1 * t1) : zz,
                              qz ? (__bf16)__expf(-10.f * t2 * t2) : zz,
                              qz ? (__bf16)__expf(-10.f * t3 * t3) : zz,
                              zz, zz, zz, zz };
        }
#pragma unroll
        for (int nt = 0; nt < 8; ++nt) {
            bf16x8 b = pB1[(7 * 4 + q) * 128 + nt * 16 + ln];
            acc1[0][nt] = __builtin_amdgcn_mfma_f32_16x16x32_bf16(a[0], b, acc1[0][nt], 0, 0, 0);
            acc1[1][nt] = __builtin_amdgcn_mfma_f32_16x16x32_bf16(a[1], b, acc1[1][nt], 0, 0, 0);
        }
    }

    // ---- SiLU + wave-private transpose (C-layout -> row-major bf16) ----
    __bf16* Hw = &Hs[w * WEDGES * LDH2];
#pragma unroll
    for (int mt = 0; mt < 2; ++mt)
#pragma unroll
        for (int nt = 0; nt < 8; ++nt)
#pragma unroll
            for (int r = 0; r < 4; ++r) {
                float z = acc1[mt][nt][r];
                float s = z / (1.0f + __expf(-z));
                Hw[(mt * 16 + q * 4 + r) * LDH2 + nt * 16 + ln] = (__bf16)s;
            }
    // Same-wave LDS RAW: compiler inserts lgkmcnt waits; no __syncthreads needed.

    // ---- Layer 2: [32 x 128] @ [128 x 64] ----
    fx4 acc2[2][4];
#pragma unroll
    for (int mt = 0; mt < 2; ++mt)
#pragma unroll
        for (int nt = 0; nt < 4; ++nt)
            acc2[mt][nt] = (fx4){0.f, 0.f, 0.f, 0.f};

    const bf16x8* pB2 = (const bf16x8*)B2;
#pragma unroll
    for (int kk = 0; kk < 4; ++kk) {
        bf16x8 a2[2];
#pragma unroll
        for (int mt = 0; mt < 2; ++mt)
            a2[mt] = *(const bf16x8*)&Hw[(mt * 16 + ln) * LDH2 + kk * 32 + q * 8];
#pragma unroll
        for (int nt = 0; nt < 4; ++nt) {
            bf16x8 b2 = pB2[(kk * 4 + q) * 64 + nt * 16 + ln];
            acc2[0][nt] = __builtin_amdgcn_mfma_f32_16x16x32_bf16(a2[0], b2, acc2[0][nt], 0, 0, 0);
            acc2[1][nt] = __builtin_amdgcn_mfma_f32_16x16x32_bf16(a2[1], b2, acc2[1][nt], 0, 0, 0);
        }
    }

    // ---- Store ----
#pragma unroll
    for (int mt = 0; mt < 2; ++mt)
#pragma unroll
        for (int nt = 0; nt < 4; ++nt)
#pragma unroll
            for (int r = 0; r < 4; ++r)
                out[(size_t)(g0 + mt * 16 + q * 4 + r) * ODIM + nt * 16 + ln] = acc2[mt][nt][r];
}

extern "C" void kernel_launch(void* const* d_in, const int* in_sizes, int n_in,
                              void* d_out, int out_size, void* d_ws, size_t ws_size,
                              hipStream_t stream) {
    const float* h   = (const float*)d_in[0];
    const int*   src = (const int*)d_in[1];
    const int*   dst = (const int*)d_in[2];
    const float* en  = (const float*)d_in[3];
    const float* mu  = (const float*)d_in[4];
    const float* W1  = (const float*)d_in[5];
    const float* W2  = (const float*)d_in[6];

    __bf16* B1 = (__bf16*)d_ws;                          // 32768 bf16 = 64 KB
    __bf16* B2 = (__bf16*)((char*)d_ws + 65536);         // 8192 bf16  = 16 KB

    pack_w<<<160, 256, 0, stream>>>(W1, W2, B1, B2);

    const int E = in_sizes[1];                 // 800000
    const int nblocks = E / BEDGES;            // 6250
    edges_fused<<<nblocks, 256, 0, stream>>>(h, src, dst, en, mu, B1, B2, (float*)d_out);
}